// Round 1
// 333.167 us; speedup vs baseline: 1.0699x; 1.0699x over previous
//
#include <hip/hip_runtime.h>
#include <hip/hip_bf16.h>

#define NQ 4096
#define NK 8192
#define DQK 256
#define DA 64
#define NH 4
#define DOUT 256
#define KSPLIT 16
#define KLEN (NK / KSPLIT)   // 512 keys per split
#define NQT (NQ / 32)        // 128 q-tiles of 32
#define NSUP 4               // split-groups surviving to combine (16/4 waves)
#define LOG2E 1.44269504088896340736f
#define QSCALE (0.125f * LOG2E)   // 1/sqrt(64) * log2(e), folded into Qp

typedef __attribute__((ext_vector_type(8))) short bf16x8;
typedef __attribute__((ext_vector_type(4))) float f32x4;
typedef __attribute__((ext_vector_type(4))) _Float16 f16x4;
typedef __attribute__((ext_vector_type(8))) _Float16 f16x8;

__device__ inline unsigned short f2bf(float f) {
  union { float f; unsigned u; } v; v.f = f;
  unsigned r = v.u + 0x7fff + ((v.u >> 16) & 1);  // RNE
  return (unsigned short)(r >> 16);
}

// ---------------------------------------------------------------------------
// 1. mask (int32 NQ x NK) -> TRANSPOSED bitmask bitsT[word32][row] (4 MB).
//    attn then reads 16 consecutive rows' words as one 64B segment.
// ---------------------------------------------------------------------------
__global__ __launch_bounds__(256) void maskbits_kernel(
    const int* __restrict__ mask, unsigned* __restrict__ bitsT) {
  const int NW = 8192 * 4;                       // total waves
  int wid = blockIdx.x * 4 + (threadIdx.x >> 6);
  int lane = threadIdx.x & 63;
  for (int j = 0; j < 2; ++j) {
    int v[8];
#pragma unroll
    for (int u = 0; u < 8; ++u) {
      int c = wid + (j * 8 + u) * NW;   // u64 chunk id: row = c>>7, ch = c&127
      v[u] = mask[(size_t)(c >> 7) * NK + (c & 127) * 64 + lane];
    }
#pragma unroll
    for (int u = 0; u < 8; ++u) {
      unsigned long long b = __ballot(v[u] != 0);
      int c = wid + (j * 8 + u) * NW;
      int n = c >> 7, ch = c & 127;
      if (lane == 0)  bitsT[(size_t)(2 * ch) * NQ + n] = (unsigned)b;
      if (lane == 32) bitsT[(size_t)(2 * ch + 1) * NQ + n] = (unsigned)(b >> 32);
    }
  }
}

// ---------------------------------------------------------------------------
// 2. projections: Q = xQ@Wq[h] * QSCALE -> Qp[h][n][d] bf16 (scale folded)
//                 K = xK@Wk[h] -> Kp[h][m][d] bf16
//                 V -> Vf f16 in K=32 fragment-linear order: per 32-key tile,
//                 per d-tile dt, each lane stores f16x8 = {keys quad*4+r of
//                 sub-tile 0, keys 16+quad*4+r of sub-tile 1} — exactly the
//                 A-frag the PV mfma_f32_16x16x32_f16 consumes (A/B use the
//                 same k-permutation, so any bijection is valid).
//    640 blocks (128 rows each) instead of 320: the old grid left the CUs at
//    ~1.25 waves/SIMD — pure latency exposure.
// ---------------------------------------------------------------------------
__global__ __launch_bounds__(256) void proj_kernel(
    const float* __restrict__ xQ, const float* __restrict__ xK,
    const float* __restrict__ Wq, const float* __restrict__ Wk,
    const float* __restrict__ Wv,
    unsigned short* __restrict__ Qp, unsigned short* __restrict__ Kp,
    _Float16* __restrict__ Vf) {
  __shared__ __align__(16) unsigned short Wt[64][264];  // Wt[d][c], padded

  int b = blockIdx.x;
  int proj, h, rb;
  if (b < 128)       { proj = 0; h = b >> 5;  rb = b & 31; }
  else if (b < 384)  { proj = 1; b -= 128; h = b >> 6; rb = b & 63; }
  else               { proj = 2; b -= 384; h = b >> 6; rb = b & 63; }
  const float* x = (proj == 0) ? xQ : xK;
  const float* W = (proj == 0 ? Wq : (proj == 1 ? Wk : Wv)) + (size_t)h * 256 * 64;

  for (int i = threadIdx.x; i < 16384; i += 256)
    Wt[i & 63][i >> 6] = f2bf(W[i]);
  __syncthreads();

  int lane = threadIdx.x & 63, wv = threadIdx.x >> 6;
  int quad = lane >> 4, n16 = lane & 15;
  int r0 = rb * 128 + wv * 32;          // 32 rows per wave

  f32x4 acc[2][4];
#pragma unroll
  for (int mt = 0; mt < 2; ++mt)
#pragma unroll
    for (int nt = 0; nt < 4; ++nt)
      acc[mt][nt] = (f32x4){0.f, 0.f, 0.f, 0.f};

#pragma unroll
  for (int it = 0; it < 8; ++it) {
    const int k0 = it * 32;
    bf16x8 af[2];
#pragma unroll
    for (int mt = 0; mt < 2; ++mt) {
      const float* xp = x + (size_t)(r0 + mt * 16 + n16) * 256 + k0 + quad * 8;
      const float4 a0 = *(const float4*)xp;
      const float4 a1 = *(const float4*)(xp + 4);
      bf16x8 a;
      a[0] = (short)f2bf(a0.x); a[1] = (short)f2bf(a0.y);
      a[2] = (short)f2bf(a0.z); a[3] = (short)f2bf(a0.w);
      a[4] = (short)f2bf(a1.x); a[5] = (short)f2bf(a1.y);
      a[6] = (short)f2bf(a1.z); a[7] = (short)f2bf(a1.w);
      af[mt] = a;
    }
    bf16x8 bfr[4];
#pragma unroll
    for (int nt = 0; nt < 4; ++nt)
      bfr[nt] = *(const bf16x8*)&Wt[nt * 16 + n16][k0 + quad * 8];
#pragma unroll
    for (int mt = 0; mt < 2; ++mt)
#pragma unroll
      for (int nt = 0; nt < 4; ++nt)
        acc[mt][nt] = __builtin_amdgcn_mfma_f32_16x16x32_bf16(
            af[mt], bfr[nt], acc[mt][nt], 0, 0, 0);
  }

  if (proj < 2) {
    unsigned short* outp =
        (proj == 0 ? Qp : Kp) + (size_t)h * (size_t)(proj == 0 ? NQ : NK) * 64;
    const float sc = (proj == 0) ? QSCALE : 1.0f;
#pragma unroll
    for (int mt = 0; mt < 2; ++mt)
#pragma unroll
      for (int nt = 0; nt < 4; ++nt)
#pragma unroll
        for (int r = 0; r < 4; ++r) {
          int row = r0 + mt * 16 + quad * 4 + r;
          int col = nt * 16 + n16;
          outp[(size_t)row * 64 + col] = f2bf(acc[mt][nt][r] * sc);
        }
  } else {
    // K=32 fragment-linear V: tile = h*256 + keyblock32; frag dt holds
    // lane's f16x8 = {acc[mt0][dt][0..3], acc[mt1][dt][0..3]} (16B stores)
    int tile = h * 256 + (r0 >> 5);     // r0 is 32-aligned, mt0/mt1 same tile
#pragma unroll
    for (int nt = 0; nt < 4; ++nt) {
      f16x8 pk;
      pk[0] = (_Float16)acc[0][nt][0]; pk[1] = (_Float16)acc[0][nt][1];
      pk[2] = (_Float16)acc[0][nt][2]; pk[3] = (_Float16)acc[0][nt][3];
      pk[4] = (_Float16)acc[1][nt][0]; pk[5] = (_Float16)acc[1][nt][1];
      pk[6] = (_Float16)acc[1][nt][2]; pk[7] = (_Float16)acc[1][nt][3];
      *(f16x8*)&Vf[(((size_t)tile * 4 + nt) * 64 + lane) * 8] = pk;
    }
  }
}

// ---------------------------------------------------------------------------
// 3. flash attention, S^T formulation, fixed max, in-register P.
//    Changes vs previous version:
//    - XCD-chunked block order (2048%8==0 bijection): wgid = xcd*256 + idx,
//      decode (ksg,h) major / qt minor -> each XCD touches 1 ksg x 2 h:
//      KV 1MB + bits 1MB + Q 1MB < 4MB per-XCD L2 (was ~14MB -> LLC latency).
//    - K-frags + mask bits software-prefetched one kb ahead (registers).
//    - PV uses mfma_f32_16x16x32_f16 (full-rate) with K=32 frag-linear V:
//      8 MFMAs/kb instead of 16 half-rate ones.
//    - l row-sum moved off the VALU: ones-A-frag MFMA accumulates sum(P)
//      per q column (kills ~16 VALU adds/kb + end shuffles).
// ---------------------------------------------------------------------------
__global__ __launch_bounds__(256, 4) void attn_kernel(
    const unsigned short* __restrict__ Qp, const unsigned short* __restrict__ Kp,
    const _Float16* __restrict__ Vf, const unsigned* __restrict__ bitsT,
    _Float16* __restrict__ Opart, float* __restrict__ Lpart) {
  __shared__ __align__(16) float Ob[32][68];   // +4 pad: conflict-free cols
  __shared__ float Lb[32];

  // XCD-chunked bijective swizzle (8 XCDs, 2048 blocks, 256/chunk)
  int orig = blockIdx.x;
  int wgid = (orig & 7) * 256 + (orig >> 3);
  int qt = wgid & 127;
  int combo = wgid >> 7;          // ksg*4 + h: each XCD owns 2 combos, same ksg
  int h = combo & 3, ksg = combo >> 2;

  int wv = threadIdx.x >> 6, lane = threadIdx.x & 63;
  int quad = lane >> 4, n16 = lane & 15;
  int ks = ksg * 4 + wv;          // this wave's key-split (of 16)
  int qb = qt * 32;

  // Q frags (bf16, pre-scaled by QSCALE)
  bf16x8 qf[2][2];
#pragma unroll
  for (int qc = 0; qc < 2; ++qc)
#pragma unroll
    for (int c = 0; c < 2; ++c)
      qf[qc][c] = *(const bf16x8*)&Qp[((size_t)h * NQ + qb + qc * 16 + n16) * 64 +
                                      c * 32 + quad * 8];

  f32x4 o[4][2];
#pragma unroll
  for (int dt = 0; dt < 4; ++dt)
#pragma unroll
    for (int qc = 0; qc < 2; ++qc) o[dt][qc] = (f32x4){0.f, 0.f, 0.f, 0.f};
  f32x4 o_l[2];
  o_l[0] = (f32x4){0.f, 0.f, 0.f, 0.f};
  o_l[1] = (f32x4){0.f, 0.f, 0.f, 0.f};

  f16x8 vones;
#pragma unroll
  for (int i = 0; i < 8; ++i) vones[i] = (_Float16)1.0f;

  const unsigned short* Kptr =
      Kp + (size_t)h * NK * 64 + (size_t)(ks * KLEN + n16) * 64 + quad * 8;
  const _Float16* Vbase = Vf + ((size_t)h * 256 + ks * 16) * 2048 + lane * 8;
  const unsigned* bT = bitsT + (size_t)(ks * 16) * NQ + qb;

  const int NKB = KLEN / 32;   // 16

  auto body = [&](int kb, const bf16x8 (&kf)[2][2], unsigned wqa0, unsigned wqa1) {
    // V A-frags: K=32 fragment-linear, 16B loads (consumed last -> latency
    // hidden under QK + exp)
    const _Float16* Vg = Vbase + (size_t)kb * 2048;
    f16x8 vf8[4];
#pragma unroll
    for (int dt = 0; dt < 4; ++dt)
      vf8[dt] = *(const f16x8*)(Vg + dt * 512);

    // S^T = K·Q^T (bf16 K=32, pre-scaled)
    f32x4 s[2][2];
#pragma unroll
    for (int kr = 0; kr < 2; ++kr)
#pragma unroll
      for (int qc = 0; qc < 2; ++qc) {
        f32x4 acc = (f32x4){0.f, 0.f, 0.f, 0.f};
        acc = __builtin_amdgcn_mfma_f32_16x16x32_bf16(kf[kr][0], qf[qc][0], acc, 0, 0, 0);
        acc = __builtin_amdgcn_mfma_f32_16x16x32_bf16(kf[kr][1], qf[qc][1], acc, 0, 0, 0);
        s[kr][qc] = acc;
      }

    // P = exp2(S^T) masked -> f16x8 B-frag (kr0 in elems 0..3, kr1 in 4..7,
    // matching the V storage permutation)
#pragma unroll
    for (int qc = 0; qc < 2; ++qc) {
      unsigned wq = (qc == 0 ? wqa0 : wqa1) >> (quad * 4);
      f16x8 pf8;
#pragma unroll
      for (int kr = 0; kr < 2; ++kr) {
        float e0 = __builtin_amdgcn_exp2f(s[kr][qc][0]);
        float e1 = __builtin_amdgcn_exp2f(s[kr][qc][1]);
        float e2 = __builtin_amdgcn_exp2f(s[kr][qc][2]);
        float e3 = __builtin_amdgcn_exp2f(s[kr][qc][3]);
        e0 = (wq & (1u << (kr * 16 + 0))) ? e0 : 0.f;
        e1 = (wq & (1u << (kr * 16 + 1))) ? e1 : 0.f;
        e2 = (wq & (1u << (kr * 16 + 2))) ? e2 : 0.f;
        e3 = (wq & (1u << (kr * 16 + 3))) ? e3 : 0.f;
        pf8[kr * 4 + 0] = (_Float16)e0; pf8[kr * 4 + 1] = (_Float16)e1;
        pf8[kr * 4 + 2] = (_Float16)e2; pf8[kr * 4 + 3] = (_Float16)e3;
      }
      // l-sum on the MFMA pipe: ones-A-frag, every reg of o_l = sum_k P[k][q]
      o_l[qc] = __builtin_amdgcn_mfma_f32_16x16x32_f16(vones, pf8, o_l[qc], 0, 0, 0);
#pragma unroll
      for (int dt = 0; dt < 4; ++dt)
        o[dt][qc] = __builtin_amdgcn_mfma_f32_16x16x32_f16(vf8[dt], pf8,
                                                           o[dt][qc], 0, 0, 0);
    }
  };

  // ---- software-pipelined K-loop: prefetch K-frags + bits one kb ahead
  unsigned cw0 = bT[n16], cw1 = bT[16 + n16];
  bf16x8 ck[2][2];
#pragma unroll
  for (int kr = 0; kr < 2; ++kr)
#pragma unroll
    for (int c = 0; c < 2; ++c)
      ck[kr][c] = *(const bf16x8*)(Kptr + kr * 16 * 64 + c * 32);

#pragma unroll 2
  for (int kb = 0; kb < NKB - 1; ++kb) {
    unsigned nw0 = bT[(size_t)(kb + 1) * NQ + n16];
    unsigned nw1 = bT[(size_t)(kb + 1) * NQ + 16 + n16];
    const unsigned short* Kg = Kptr + (size_t)(kb + 1) * 2048;
    bf16x8 nk[2][2];
#pragma unroll
    for (int kr = 0; kr < 2; ++kr)
#pragma unroll
      for (int c = 0; c < 2; ++c)
        nk[kr][c] = *(const bf16x8*)(Kg + kr * 16 * 64 + c * 32);

    body(kb, ck, cw0, cw1);

#pragma unroll
    for (int kr = 0; kr < 2; ++kr)
#pragma unroll
      for (int c = 0; c < 2; ++c) ck[kr][c] = nk[kr][c];
    cw0 = nw0; cw1 = nw1;
  }
  body(NKB - 1, ck, cw0, cw1);

  float ls[2];
  ls[0] = o_l[0][0];    // every lane holds the full column sum for its q=n16
  ls[1] = o_l[1][0];

  // ---- in-block reduction over the 4 splits (sequential barriered phases)
#pragma unroll
  for (int w = 0; w < 4; ++w) {
    if (wv == w) {
      if (w == 0) {
#pragma unroll
        for (int qc = 0; qc < 2; ++qc)
#pragma unroll
          for (int dt = 0; dt < 4; ++dt)
            *(f32x4*)&Ob[qc * 16 + n16][dt * 16 + quad * 4] = o[dt][qc];
        if (quad == 0) { Lb[n16] = ls[0]; Lb[16 + n16] = ls[1]; }
      } else {
#pragma unroll
        for (int qc = 0; qc < 2; ++qc)
#pragma unroll
          for (int dt = 0; dt < 4; ++dt) {
            f32x4 t = *(f32x4*)&Ob[qc * 16 + n16][dt * 16 + quad * 4];
            t += o[dt][qc];
            *(f32x4*)&Ob[qc * 16 + n16][dt * 16 + quad * 4] = t;
          }
        if (quad == 0) { Lb[n16] += ls[0]; Lb[16 + n16] += ls[1]; }
      }
    }
    __syncthreads();
  }

  // cooperative coalesced store: tile = (h*NQT+qt)*NSUP + ksg
  const size_t tile = ((size_t)h * NQT + qt) * NSUP + ksg;
  {
    int tid = threadIdx.x;
    int r = tid >> 3, c0 = (tid & 7) * 8;
    f32x4 a = *(f32x4*)&Ob[r][c0];
    f32x4 b2 = *(f32x4*)&Ob[r][c0 + 4];
    f16x8 ov;
    ov[0] = (_Float16)a[0]; ov[1] = (_Float16)a[1];
    ov[2] = (_Float16)a[2]; ov[3] = (_Float16)a[3];
    ov[4] = (_Float16)b2[0]; ov[5] = (_Float16)b2[1];
    ov[6] = (_Float16)b2[2]; ov[7] = (_Float16)b2[3];
    *(f16x8*)&Opart[(tile * 32 + r) * 64 + c0] = ov;
    if (tid < 32) Lpart[tile * 32 + tid] = Lb[tid];
  }
}

// ---------------------------------------------------------------------------
// 4. combine NSUP partials + fused gates + @Wo + bo. 256 blocks x 16 rows
// ---------------------------------------------------------------------------
__global__ __launch_bounds__(256) void combine_kernel(
    const _Float16* __restrict__ Opart, const float* __restrict__ Lpart,
    const float* __restrict__ xQ, const float* __restrict__ Wg,
    const float* __restrict__ bg, const float* __restrict__ Wo,
    const float* __restrict__ bo, float* __restrict__ out) {
  __shared__ float comb[16][64];
  __shared__ float gred[16][4][4];
  __shared__ float glds[16][4];
  int nb = blockIdx.x;
  int tid = threadIdx.x;

  // gates for this block's 16 rows
  {
    int r = tid >> 4, hh = (tid >> 2) & 3, c = tid & 3;
    const float* xp = xQ + (size_t)(nb * 16 + r) * 256 + c * 64;
    const float* wp = Wg + hh * 256 + c * 64;
    float s = 0.f;
#pragma unroll
    for (int e = 0; e < 64; ++e) s = fmaf(xp[e], wp[e], s);
    gred[r][hh][c] = s;
  }
  __syncthreads();
  if (tid < 64) {
    int r = tid >> 2, hh = tid & 3;
    float s = gred[r][hh][0] + gred[r][hh][1] + gred[r][hh][2] + gred[r][hh][3];
    glds[r][hh] = 1.f / (1.f + __expf(-(s + bg[hh])));
  }
  __syncthreads();

  int r4 = tid >> 6, a = tid & 63;
  int qt = nb >> 1, rbase = (nb & 1) * 16;

  for (int p = 0; p < 4; ++p) {
    int r = p * 4 + r4;
    int rl = rbase + r;
    float csum = 0.f;
#pragma unroll
    for (int h = 0; h < NH; ++h) {
      size_t t0 = ((size_t)h * NQT + qt) * NSUP;
      float accO = 0.f, lt = 0.f;
#pragma unroll
      for (int s = 0; s < NSUP; ++s) {
        size_t t = t0 + s;
        accO += (float)Opart[(t * 32 + rl) * 64 + a];
        lt += Lpart[t * 32 + rl];
      }
      csum += glds[r][h] * accO / lt;
    }
    comb[r][a] = csum;
  }
  __syncthreads();

  int j = tid;
  float accv[16];
#pragma unroll
  for (int r = 0; r < 16; ++r) accv[r] = bo[j];
  for (int aa = 0; aa < 64; ++aa) {
    float w = Wo[(size_t)aa * 256 + j];
#pragma unroll
    for (int r = 0; r < 16; ++r) accv[r] = fmaf(comb[r][aa], w, accv[r]);
  }
#pragma unroll
  for (int r = 0; r < 16; ++r)
    out[(size_t)(nb * 16 + r) * 256 + j] = accv[r];
}

// ---------------------------------------------------------------------------
extern "C" void kernel_launch(void* const* d_in, const int* in_sizes, int n_in,
                              void* d_out, int out_size, void* d_ws, size_t ws_size,
                              hipStream_t stream) {
  const float* xQ  = (const float*)d_in[0];
  const float* xK  = (const float*)d_in[1];
  const int*   mask= (const int*)d_in[2];
  const float* Wq  = (const float*)d_in[3];
  const float* Wk  = (const float*)d_in[4];
  const float* Wv  = (const float*)d_in[5];
  const float* Wg  = (const float*)d_in[6];
  const float* bg  = (const float*)d_in[7];
  const float* Wo  = (const float*)d_in[8];
  const float* bo  = (const float*)d_in[9];
  float* out = (float*)d_out;

  char* ws = (char*)d_ws;
  unsigned short* Qp   = (unsigned short*)(ws + 0);         // 2 MB  [H][NQ][64]
  unsigned short* Kp   = (unsigned short*)(ws + 2097152);   // 4 MB  [H][NK][64]
  _Float16*       Vfp  = (_Float16*)(ws + 6291456);         // 4 MB  frag-linear
  unsigned*       bitsT= (unsigned*)(ws + 10485760);        // 4 MB  [word][row]
  float*          Lp   = (float*)(ws + 14680064);           // 256 KB
  _Float16*       Op   = (_Float16*)(ws + 14942208);        // 8.4 MB f16

  maskbits_kernel<<<dim3(8192), dim3(256), 0, stream>>>(mask, bitsT);
  proj_kernel<<<dim3(640), dim3(256), 0, stream>>>(xQ, xK, Wq, Wk, Wv, Qp, Kp, Vfp);
  attn_kernel<<<dim3(2048), dim3(256), 0, stream>>>(Qp, Kp, Vfp, bitsT, Op, Lp);
  combine_kernel<<<dim3(NQ / 16), dim3(256), 0, stream>>>(Op, Lp, xQ, Wg, bg,
                                                          Wo, bo, out);
}